// Round 4
// baseline (81.540 us; speedup 1.0000x reference)
//
#include <hip/hip_runtime.h>

#define N_NODES 8192
#define WORDS_PER_ROW 256   // 8192 bits / 32
#define C 64

// ---------------------------------------------------------------------------
// 1) Edge scatter into a dense bitmap. atomicOr is idempotent => set semantics
//    (duplicate edges collapse to 1) and deterministic output.
// ---------------------------------------------------------------------------
__global__ __launch_bounds__(256) void scatter_edges(const int* __restrict__ e, int E,
                              unsigned* __restrict__ bitmap) {
    int i = blockIdx.x * blockDim.x + threadIdx.x;
    if (i < E) {
        int r = e[i];        // edge_index[0][i]
        int c = e[i + E];    // edge_index[1][i]
        atomicOr(&bitmap[r * WORDS_PER_ROW + (c >> 5)], 1u << (c & 31));
    }
}

// ---------------------------------------------------------------------------
// 2) degree[r] = popcount(row r) + 1 (the +1 is the added eye; a self-loop
//    edge's bit is already in the popcount, matching adj[r][r] == 2.0).
//    dinv[r] = degree^-0.5  (degree >= 1 always, no zero check needed).
//    One wave (64 lanes) per row; each lane popcounts one uint4 (128 bits).
// ---------------------------------------------------------------------------
__global__ __launch_bounds__(64) void degree_kernel(const unsigned* __restrict__ bitmap,
                              float* __restrict__ dinv) {
    int r = blockIdx.x;
    int lane = threadIdx.x;
    const uint4* row = (const uint4*)(bitmap + r * WORDS_PER_ROW);
    uint4 v = row[lane];
    int cnt = __popc(v.x) + __popc(v.y) + __popc(v.z) + __popc(v.w);
#pragma unroll
    for (int off = 32; off; off >>= 1) cnt += __shfl_down(cnt, off);
    if (lane == 0) dinv[r] = 1.0f / sqrtf((float)(cnt + 1));
}

// ---------------------------------------------------------------------------
// 3) y = x @ W^T   (linear applied BEFORE aggregation: norm_adj@(xW^T) ==
//    (norm_adj@x)@W^T). W staged transposed in LDS => lane o reads
//    Wt[k*64+o], consecutive across lanes, conflict-free.
// ---------------------------------------------------------------------------
__global__ __launch_bounds__(256) void gemm_xw(const float* __restrict__ x, const float* __restrict__ W,
                        float* __restrict__ y) {
    __shared__ float Wt[C * C];
    int tid = threadIdx.x;  // 256
    for (int i = tid; i < C * C; i += 256) {
        int o = i >> 6, k = i & 63;
        Wt[k * C + o] = W[i];
    }
    __syncthreads();
    int o = tid & 63;
    int rloc = tid >> 6;                        // 4 rows per block
    int r = blockIdx.x * 4 + rloc;              // grid covers all rows
    const float* xr = x + r * C;
    float acc = 0.0f;
#pragma unroll
    for (int k = 0; k < C; ++k) acc += xr[k] * Wt[k * C + o];
    y[r * C + o] = acc;
}

// ---------------------------------------------------------------------------
// 4) out[r][:] = dinv[r] * ( sum_{c in row bits} dinv[c]*y[c][:]
//                            + dinv[r]*y[r][:] )   + b
//    One wave per row, lane = output channel. y (2 MB) is L2/L3 resident,
//    so the random row gathers are cache hits.
// ---------------------------------------------------------------------------
__global__ __launch_bounds__(256) void spmm_kernel(const unsigned* __restrict__ bitmap,
                            const float* __restrict__ dinv,
                            const float* __restrict__ y,
                            const float* __restrict__ b,
                            float* __restrict__ out) {
    int wave = threadIdx.x >> 6;
    int lane = threadIdx.x & 63;
    int r = blockIdx.x * 4 + wave;
    const uint4* row = (const uint4*)(bitmap + r * WORDS_PER_ROW);
    float dr = dinv[r];
    float acc = dr * y[r * C + lane];  // eye term (weight dinv[r], outer dinv[r] applied below)
    for (int w4 = 0; w4 < WORDS_PER_ROW / 4; ++w4) {
        uint4 v = row[w4];
        int base = w4 * 128;
        unsigned bits;
        bits = v.x;
        while (bits) { int c = base       + __builtin_ctz(bits); bits &= bits - 1; acc += dinv[c] * y[c * C + lane]; }
        bits = v.y;
        while (bits) { int c = base + 32  + __builtin_ctz(bits); bits &= bits - 1; acc += dinv[c] * y[c * C + lane]; }
        bits = v.z;
        while (bits) { int c = base + 64  + __builtin_ctz(bits); bits &= bits - 1; acc += dinv[c] * y[c * C + lane]; }
        bits = v.w;
        while (bits) { int c = base + 96  + __builtin_ctz(bits); bits &= bits - 1; acc += dinv[c] * y[c * C + lane]; }
    }
    out[r * C + lane] = dr * acc + b[lane];
}

// ---------------------------------------------------------------------------
extern "C" void kernel_launch(void* const* d_in, const int* in_sizes, int n_in,
                              void* d_out, int out_size, void* d_ws, size_t ws_size,
                              hipStream_t stream) {
    const float* x  = (const float*)d_in[0];   // [8192, 64]
    const int*   ei = (const int*)d_in[1];     // [2, E] flat
    const float* W  = (const float*)d_in[2];   // [64, 64]
    const float* b  = (const float*)d_in[3];   // [64]
    float* out = (float*)d_out;                // [8192, 64]
    int E = in_sizes[1] / 2;

    // workspace layout: bitmap (8 MB) | dinv (32 KB) | y (2 MB)
    unsigned* bitmap = (unsigned*)d_ws;
    float* dinv = (float*)((char*)d_ws + (size_t)N_NODES * WORDS_PER_ROW * 4);
    float* y    = dinv + N_NODES;

    hipMemsetAsync(bitmap, 0, (size_t)N_NODES * WORDS_PER_ROW * 4, stream);
    scatter_edges<<<(E + 255) / 256, 256, 0, stream>>>(ei, E, bitmap);
    degree_kernel<<<N_NODES, 64, 0, stream>>>(bitmap, dinv);
    gemm_xw<<<N_NODES / 4, 256, 0, stream>>>(x, W, y);
    spmm_kernel<<<N_NODES / 4, 256, 0, stream>>>(bitmap, dinv, y, b, out);
}

// Round 5
// 75.789 us; speedup vs baseline: 1.0759x; 1.0759x over previous
//
#include <hip/hip_runtime.h>

#define N_NODES 8192
#define WORDS_PER_ROW 256   // 8192 bits / 32
#define C 64
#define GEMM_BLOCKS 2048    // 4 rows per 256-thread block

// ---------------------------------------------------------------------------
// 0) Zero the 8 MB bitmap. One uint4 store per thread, 2048*256*16B = 8 MB.
//    Replaces hipMemsetAsync's rocclr fill kernel which ran at ~0.2 TB/s
//    (~40 us = half the round-4 total).
// ---------------------------------------------------------------------------
__global__ __launch_bounds__(256) void zero_bitmap(uint4* __restrict__ bm4) {
    int i = blockIdx.x * 256 + threadIdx.x;
    bm4[i] = make_uint4(0u, 0u, 0u, 0u);
}

// ---------------------------------------------------------------------------
// 1) Edge scatter into the dense bitmap. atomicOr is idempotent => set
//    semantics (duplicate edges collapse to 1) and deterministic output.
// ---------------------------------------------------------------------------
__global__ __launch_bounds__(256) void scatter_edges(const int* __restrict__ e, int E,
                              unsigned* __restrict__ bitmap) {
    int i = blockIdx.x * blockDim.x + threadIdx.x;
    if (i < E) {
        int r = e[i];        // edge_index[0][i]
        int c = e[i + E];    // edge_index[1][i]
        atomicOr(&bitmap[r * WORDS_PER_ROW + (c >> 5)], 1u << (c & 31));
    }
}

// ---------------------------------------------------------------------------
// 2+3 merged (independent work, block-role split on blockIdx):
//    blocks [0, GEMM_BLOCKS)        : y = x @ W^T  (4 rows per block)
//    blocks [GEMM_BLOCKS, 2*GEMM_BLOCKS): degree/dinv (4 rows per block,
//                                        one wave per row)
//    degree[r] = popcount(row r) + 1 (the +1 is the added eye; a self-loop
//    edge's bit is already counted, matching adj[r][r] == 2.0).
// ---------------------------------------------------------------------------
__global__ __launch_bounds__(256) void degree_gemm(const unsigned* __restrict__ bitmap,
                               const float* __restrict__ x,
                               const float* __restrict__ W,
                               float* __restrict__ y,
                               float* __restrict__ dinv) {
    int tid = threadIdx.x;
    if (blockIdx.x < GEMM_BLOCKS) {
        // ---- GEMM role: W staged transposed in LDS, conflict-free reads.
        __shared__ float Wt[C * C];
        for (int i = tid; i < C * C; i += 256) {
            int o = i >> 6, k = i & 63;
            Wt[k * C + o] = W[i];
        }
        __syncthreads();
        int o = tid & 63;
        int r = blockIdx.x * 4 + (tid >> 6);
        const float* xr = x + r * C;
        float acc = 0.0f;
#pragma unroll
        for (int k = 0; k < C; ++k) acc += xr[k] * Wt[k * C + o];
        y[r * C + o] = acc;
    } else {
        // ---- degree role: one wave per row, each lane popcounts one uint4.
        int wave = tid >> 6;
        int lane = tid & 63;
        int r = (blockIdx.x - GEMM_BLOCKS) * 4 + wave;
        const uint4* row = (const uint4*)(bitmap + r * WORDS_PER_ROW);
        uint4 v = row[lane];
        int cnt = __popc(v.x) + __popc(v.y) + __popc(v.z) + __popc(v.w);
#pragma unroll
        for (int off = 32; off; off >>= 1) cnt += __shfl_down(cnt, off);
        if (lane == 0) dinv[r] = 1.0f / sqrtf((float)(cnt + 1));
    }
}

// ---------------------------------------------------------------------------
// 4) out[r][:] = dinv[r] * ( sum_{c in row bits} dinv[c]*y[c][:]
//                            + dinv[r]*y[r][:] )   + b
//    One wave per row, lane = output channel. y (2 MB) and bitmap (8 MB) are
//    L2/L3 resident, so the random row gathers are cache hits.
// ---------------------------------------------------------------------------
__global__ __launch_bounds__(256) void spmm_kernel(const unsigned* __restrict__ bitmap,
                            const float* __restrict__ dinv,
                            const float* __restrict__ y,
                            const float* __restrict__ b,
                            float* __restrict__ out) {
    int wave = threadIdx.x >> 6;
    int lane = threadIdx.x & 63;
    int r = blockIdx.x * 4 + wave;
    const uint4* row = (const uint4*)(bitmap + r * WORDS_PER_ROW);
    float dr = dinv[r];
    float acc = dr * y[r * C + lane];  // eye term (outer dinv[r] applied below)
    for (int w4 = 0; w4 < WORDS_PER_ROW / 4; ++w4) {
        uint4 v = row[w4];
        int base = w4 * 128;
        unsigned bits;
        bits = v.x;
        while (bits) { int c = base       + __builtin_ctz(bits); bits &= bits - 1; acc += dinv[c] * y[c * C + lane]; }
        bits = v.y;
        while (bits) { int c = base + 32  + __builtin_ctz(bits); bits &= bits - 1; acc += dinv[c] * y[c * C + lane]; }
        bits = v.z;
        while (bits) { int c = base + 64  + __builtin_ctz(bits); bits &= bits - 1; acc += dinv[c] * y[c * C + lane]; }
        bits = v.w;
        while (bits) { int c = base + 96  + __builtin_ctz(bits); bits &= bits - 1; acc += dinv[c] * y[c * C + lane]; }
    }
    out[r * C + lane] = dr * acc + b[lane];
}

// ---------------------------------------------------------------------------
extern "C" void kernel_launch(void* const* d_in, const int* in_sizes, int n_in,
                              void* d_out, int out_size, void* d_ws, size_t ws_size,
                              hipStream_t stream) {
    const float* x  = (const float*)d_in[0];   // [8192, 64]
    const int*   ei = (const int*)d_in[1];     // [2, E] flat
    const float* W  = (const float*)d_in[2];   // [64, 64]
    const float* b  = (const float*)d_in[3];   // [64]
    float* out = (float*)d_out;                // [8192, 64]
    int E = in_sizes[1] / 2;

    // workspace layout: bitmap (8 MB) | dinv (32 KB) | y (2 MB)
    unsigned* bitmap = (unsigned*)d_ws;
    float* dinv = (float*)((char*)d_ws + (size_t)N_NODES * WORDS_PER_ROW * 4);
    float* y    = dinv + N_NODES;

    zero_bitmap<<<2048, 256, 0, stream>>>((uint4*)bitmap);
    scatter_edges<<<(E + 255) / 256, 256, 0, stream>>>(ei, E, bitmap);
    degree_gemm<<<2 * GEMM_BLOCKS, 256, 0, stream>>>(bitmap, x, W, y, dinv);
    spmm_kernel<<<N_NODES / 4, 256, 0, stream>>>(bitmap, dinv, y, b, out);
}

// Round 6
// 51.558 us; speedup vs baseline: 1.5815x; 1.4700x over previous
//
#include <hip/hip_runtime.h>

#define N_NODES 8192
#define WPR 256     // 32-bit words per bitmap row (8192 bits)
#define C 64
#define CAP 512     // per-row neighbor-list capacity (avg degree ~32)

// ---------------------------------------------------------------------------
// 0) Zero the 8 MB bitmap: one uint4 store/thread, fully coalesced.
// ---------------------------------------------------------------------------
__global__ __launch_bounds__(256) void zero_bitmap(uint4* __restrict__ bm4) {
    int i = blockIdx.x * 256 + threadIdx.x;
    bm4[i] = make_uint4(0u, 0u, 0u, 0u);
}

// ---------------------------------------------------------------------------
// 1) Edge scatter: atomicOr is idempotent => set semantics (duplicate edges
//    collapse to 1), deterministic.
// ---------------------------------------------------------------------------
__global__ __launch_bounds__(256) void scatter_edges(const int* __restrict__ e, int E,
                              unsigned* __restrict__ bitmap) {
    int i = blockIdx.x * blockDim.x + threadIdx.x;
    if (i < E) {
        int r = e[i];        // edge_index[0][i]
        int c = e[i + E];    // edge_index[1][i]
        atomicOr(&bitmap[r * WPR + (c >> 5)], 1u << (c & 31));
    }
}

// ---------------------------------------------------------------------------
// 2) dinv[r] = (popcount(row r) + 1)^-0.5. +1 is the added eye; a self-loop
//    bit is already in the popcount (diag weight 2), matching the reference.
//    4 waves/block, one row per wave, lane popcounts one uint4.
// ---------------------------------------------------------------------------
__global__ __launch_bounds__(256) void degree_kernel(const unsigned* __restrict__ bitmap,
                               float* __restrict__ dinv) {
    int wave = threadIdx.x >> 6;
    int lane = threadIdx.x & 63;
    int r = blockIdx.x * 4 + wave;
    const uint4* row = (const uint4*)(bitmap + (size_t)r * WPR);
    uint4 v = row[lane];
    int cnt = __popc(v.x) + __popc(v.y) + __popc(v.z) + __popc(v.w);
#pragma unroll
    for (int off = 32; off; off >>= 1) cnt += __shfl_down(cnt, off);
    if (lane == 0) dinv[r] = 1.0f / sqrtf((float)(cnt + 1));
}

// ---------------------------------------------------------------------------
// 3) ys = dinv[:,None] * (x @ W^T). Pre-scaling by dinv here removes the
//    per-neighbor dinv gather+mult from the SpMM inner loop (it's free here:
//    one extra mult per output element). W transposed in LDS, conflict-free.
// ---------------------------------------------------------------------------
__global__ __launch_bounds__(256) void gemm_ys(const float* __restrict__ x,
                        const float* __restrict__ W,
                        const float* __restrict__ dinv,
                        float* __restrict__ ys) {
    __shared__ float Wt[C * C];
    int tid = threadIdx.x;
    for (int i = tid; i < C * C; i += 256) {
        int o = i >> 6, k = i & 63;
        Wt[k * C + o] = W[i];
    }
    __syncthreads();
    int o = tid & 63;
    int r = blockIdx.x * 4 + (tid >> 6);
    const float* xr = x + (size_t)r * C;
    float acc = 0.0f;
#pragma unroll
    for (int k = 0; k < C; ++k) acc += xr[k] * Wt[k * C + o];
    ys[(size_t)r * C + o] = dinv[r] * acc;
}

// ---------------------------------------------------------------------------
// 4) out[r] = dinv[r] * ( ys[r] + sum_{c in row bits} ys[c] ) + b
//    (ys[r] = dinv[r]*y[r] is exactly the eye term before the outer dinv[r].)
//    One wave/row. Phase A: lane-parallel bitmap scan -> compact LDS column
//    list (prefix-sum offsets). Phase B: pipelined coalesced gathers over the
//    list with split accumulators. Fallback serial scan if a row ever exceeds
//    CAP neighbors (correctness guarantee; never taken at avg degree 32).
// ---------------------------------------------------------------------------
__global__ __launch_bounds__(256) void spmm_kernel(const unsigned* __restrict__ bitmap,
                            const float* __restrict__ dinv,
                            const float* __restrict__ ys,
                            const float* __restrict__ b,
                            float* __restrict__ out) {
    __shared__ unsigned short list[4][CAP];
    int wave = threadIdx.x >> 6;
    int lane = threadIdx.x & 63;
    int r = blockIdx.x * 4 + wave;
    const uint4* row = (const uint4*)(bitmap + (size_t)r * WPR);
    uint4 v = row[lane];
    int myc = __popc(v.x) + __popc(v.y) + __popc(v.z) + __popc(v.w);

    // exclusive prefix sum of per-lane counts across the wave
    int pre = myc;
#pragma unroll
    for (int d = 1; d < 64; d <<= 1) {
        int t = __shfl_up(pre, d);
        if (lane >= d) pre += t;
    }
    int total = __shfl(pre, 63);
    int woff = pre - myc;
    bool uselist = (total <= CAP);

    if (uselist) {
        unsigned short* L = list[wave];
        int base = lane * 128;
        unsigned bits;
        bits = v.x;
        while (bits) { L[woff++] = (unsigned short)(base       + __builtin_ctz(bits)); bits &= bits - 1; }
        bits = v.y;
        while (bits) { L[woff++] = (unsigned short)(base + 32  + __builtin_ctz(bits)); bits &= bits - 1; }
        bits = v.z;
        while (bits) { L[woff++] = (unsigned short)(base + 64  + __builtin_ctz(bits)); bits &= bits - 1; }
        bits = v.w;
        while (bits) { L[woff++] = (unsigned short)(base + 96  + __builtin_ctz(bits)); bits &= bits - 1; }
    }
    __syncthreads();   // unconditional: all waves reach it regardless of path

    float acc = ys[(size_t)r * C + lane];   // eye term
    if (uselist) {
        const unsigned short* L = list[wave];
        float a0 = 0.f, a1 = 0.f, a2 = 0.f, a3 = 0.f;
        int i = 0;
        for (; i + 4 <= total; i += 4) {
            int c0 = L[i], c1 = L[i + 1], c2 = L[i + 2], c3 = L[i + 3];
            a0 += ys[(size_t)c0 * C + lane];
            a1 += ys[(size_t)c1 * C + lane];
            a2 += ys[(size_t)c2 * C + lane];
            a3 += ys[(size_t)c3 * C + lane];
        }
        for (; i < total; ++i) acc += ys[(size_t)L[i] * C + lane];
        acc += (a0 + a1) + (a2 + a3);
    } else {
        // fallback: serial bitmap scan (correct for any degree)
        for (int w4 = 0; w4 < WPR / 4; ++w4) {
            uint4 vv = row[w4];
            int base = w4 * 128;
            unsigned bits;
            bits = vv.x; while (bits) { int c = base       + __builtin_ctz(bits); bits &= bits - 1; acc += ys[(size_t)c * C + lane]; }
            bits = vv.y; while (bits) { int c = base + 32  + __builtin_ctz(bits); bits &= bits - 1; acc += ys[(size_t)c * C + lane]; }
            bits = vv.z; while (bits) { int c = base + 64  + __builtin_ctz(bits); bits &= bits - 1; acc += ys[(size_t)c * C + lane]; }
            bits = vv.w; while (bits) { int c = base + 96  + __builtin_ctz(bits); bits &= bits - 1; acc += ys[(size_t)c * C + lane]; }
        }
    }
    out[(size_t)r * C + lane] = dinv[r] * acc + b[lane];
}

// ---------------------------------------------------------------------------
extern "C" void kernel_launch(void* const* d_in, const int* in_sizes, int n_in,
                              void* d_out, int out_size, void* d_ws, size_t ws_size,
                              hipStream_t stream) {
    const float* x  = (const float*)d_in[0];   // [8192, 64]
    const int*   ei = (const int*)d_in[1];     // [2, E] flat
    const float* W  = (const float*)d_in[2];   // [64, 64]
    const float* b  = (const float*)d_in[3];   // [64]
    float* out = (float*)d_out;                // [8192, 64]
    int E = in_sizes[1] / 2;

    // workspace layout: bitmap (8 MB) | dinv (32 KB) | ys (2 MB)
    unsigned* bitmap = (unsigned*)d_ws;
    float* dinv = (float*)((char*)d_ws + (size_t)N_NODES * WPR * 4);
    float* ys   = dinv + N_NODES;

    zero_bitmap<<<2048, 256, 0, stream>>>((uint4*)bitmap);
    scatter_edges<<<(E + 255) / 256, 256, 0, stream>>>(ei, E, bitmap);
    degree_kernel<<<N_NODES / 4, 256, 0, stream>>>(bitmap, dinv);
    gemm_ys<<<N_NODES / 4, 256, 0, stream>>>(x, W, dinv, ys);
    spmm_kernel<<<N_NODES / 4, 256, 0, stream>>>(bitmap, dinv, ys, b, out);
}